// Round 6
// baseline (277.758 us; speedup 1.0000x reference)
//
#include <hip/hip_runtime.h>
#include <hip/hip_bf16.h>

// N=2048, D_IN=128, H=256, D_EMB=64
// inputs: 0:x 1:adj(unused) 2:W0 3:b0 4:W1 5:b1 6:W2 7:b2 8:temp 9:theta
// d_out: out[2048*128] then adj_wts[2048*2048]

typedef short bf16x8 __attribute__((ext_vector_type(8)));
typedef float f32x4 __attribute__((ext_vector_type(4)));

__device__ __forceinline__ unsigned short f2bf(float f) {
    unsigned u = __float_as_uint(f);
    unsigned r = u + 0x7fffu + ((u >> 16) & 1u);
    return (unsigned short)(r >> 16);
}

// pack 8 f32 -> bf16x8 with round-half-up
__device__ __forceinline__ bf16x8 pack_rne8(const float* p) {
    union { unsigned u[4]; bf16x8 v; } r;
    #pragma unroll
    for (int i = 0; i < 4; ++i) {
        unsigned lo = __float_as_uint(p[2 * i]) + 0x8000u;
        unsigned hi = __float_as_uint(p[2 * i + 1]) + 0x8000u;
        r.u[i] = __builtin_amdgcn_perm(hi, lo, 0x07060302u);
    }
    return r.v;
}

// truncation-pack (for the already-rounded P tile in k2)
__device__ __forceinline__ bf16x8 pack_bf8(const float* p) {
    union { unsigned u[4]; bf16x8 v; } r;
    #pragma unroll
    for (int i = 0; i < 4; ++i)
        r.u[i] = __builtin_amdgcn_perm(__float_as_uint(p[2 * i + 1]),
                                       __float_as_uint(p[2 * i]), 0x07060302u);
    return r.v;
}

// ---------------- Kernel 1: fused MLP via MFMA, 8 waves ----------------
// grid 128 x 512 thr. Block: 16 rows. GEMM0 split over 8 waves; then waves 0-3
// run GEMM1 while waves 4-7 run GEMM2 concurrently. 2 barriers. Zeroes cnt.
__global__ __launch_bounds__(512) void k1_mfma(
    const float* __restrict__ x,
    const float* __restrict__ W0, const float* __restrict__ b0,
    const float* __restrict__ W1, const float* __restrict__ b1,
    const float* __restrict__ W2, const float* __restrict__ b2,
    unsigned short* __restrict__ emb_bf,   // [2048][64] bf16
    unsigned short* __restrict__ xlT_bf,   // [128][2048] bf16
    float* __restrict__ sq,                // [2048]
    int* __restrict__ cnt)                 // [128] zeroed for k2
{
    constexpr int LDO = 264;               // out_x LDS stride (bf16 elems)
    __shared__ unsigned short oxb[16 * LDO];
    __shared__ float sqs[4][16];

    const int t = threadIdx.x;
    const int lane = t & 63;
    const int w = t >> 6;      // wave 0..7
    const int m = lane & 15;
    const int q = lane >> 4;
    const int i0 = blockIdx.x * 16;

    if (blockIdx.x == 0 && t < 128) cnt[t] = 0;

    // A-fragments of x (rows i0+m, K=128), used by GEMM0 (all waves) + GEMM2 (waves 4-7)
    bf16x8 ax[4];
    #pragma unroll
    for (int kb = 0; kb < 4; ++kb) {
        float xf[8];
        *(f32x4*)&xf[0] = *(const f32x4*)(x + (size_t)(i0 + m) * 128 + kb * 32 + q * 8);
        *(f32x4*)&xf[4] = *(const f32x4*)(x + (size_t)(i0 + m) * 128 + kb * 32 + q * 8 + 4);
        ax[kb] = pack_rne8(xf);
    }

    // ---- GEMM0: out_x = relu(x @ W0 + b0), wave w covers cols w*32..w*32+31 ----
    #pragma unroll
    for (int hh = 0; hh < 2; ++hh) {
        const int h = (w * 2 + hh) * 16 + m;
        float bb = b0[h];
        f32x4 acc = {bb, bb, bb, bb};
        #pragma unroll
        for (int kb = 0; kb < 4; ++kb) {
            float wf[8];
            #pragma unroll
            for (int j = 0; j < 8; ++j) wf[j] = W0[(size_t)(kb * 32 + q * 8 + j) * 256 + h];
            acc = __builtin_amdgcn_mfma_f32_16x16x32_bf16(ax[kb], pack_rne8(wf), acc, 0, 0, 0);
        }
        #pragma unroll
        for (int r = 0; r < 4; ++r)
            oxb[(q * 4 + r) * LDO + h] = f2bf(fmaxf(acc[r], 0.0f));
    }
    __syncthreads();

    if (w < 4) {
        // ---- GEMM1 (waves 0-3): emb = relu(out_x @ W1 + b1), cols w*16..w*16+15 ----
        const int h = w * 16 + m;
        float bb = b1[h];
        f32x4 acc = {bb, bb, bb, bb};
        #pragma unroll
        for (int kb = 0; kb < 8; ++kb) {
            bf16x8 af = *(const bf16x8*)(&oxb[m * LDO + kb * 32 + q * 8]);
            float wf[8];
            #pragma unroll
            for (int j = 0; j < 8; ++j) wf[j] = W1[(size_t)(kb * 32 + q * 8 + j) * 64 + h];
            acc = __builtin_amdgcn_mfma_f32_16x16x32_bf16(af, pack_rne8(wf), acc, 0, 0, 0);
        }
        float s2[4];
        #pragma unroll
        for (int r = 0; r < 4; ++r) {
            float e = fmaxf(acc[r], 0.0f);
            emb_bf[(size_t)(i0 + q * 4 + r) * 64 + h] = f2bf(e);
            s2[r] = e * e;
        }
        #pragma unroll
        for (int r = 0; r < 4; ++r) {
            float v = s2[r];
            v += __shfl_xor(v, 1);
            v += __shfl_xor(v, 2);
            v += __shfl_xor(v, 4);
            v += __shfl_xor(v, 8);
            if (m == 0) sqs[w][q * 4 + r] = v;
        }
    } else {
        // ---- GEMM2 (waves 4-7): x_last = x @ W2 + b2, cols (w-4)*32..+31 ----
        const int w2 = w - 4;
        #pragma unroll
        for (int hh = 0; hh < 2; ++hh) {
            const int c = (w2 * 2 + hh) * 16 + m;
            float bb = b2[c];
            f32x4 acc = {bb, bb, bb, bb};
            #pragma unroll
            for (int kb = 0; kb < 4; ++kb) {
                float wf[8];
                #pragma unroll
                for (int j = 0; j < 8; ++j) wf[j] = W2[(size_t)(kb * 32 + q * 8 + j) * 128 + c];
                acc = __builtin_amdgcn_mfma_f32_16x16x32_bf16(ax[kb], pack_rne8(wf), acc, 0, 0, 0);
            }
            uint2 pk;
            pk.x = (unsigned)f2bf(acc[0]) | ((unsigned)f2bf(acc[1]) << 16);
            pk.y = (unsigned)f2bf(acc[2]) | ((unsigned)f2bf(acc[3]) << 16);
            *(uint2*)(&xlT_bf[(size_t)c * 2048 + i0 + q * 4]) = pk;
        }
    }
    __syncthreads();
    if (t < 16)
        sq[i0 + t] = sqs[0][t] + sqs[1][t] + sqs[2][t] + sqs[3][t];
}

// ---------------- Kernel 2: fused adjacency + A@x_last + last-block reduce ----------------
// grid (128 i-tiles, 8 j-strips) x 256 thr. The 8th block to finish an i-tile
// reduces the partials and writes final out (relu(sum/deg)).
__global__ __launch_bounds__(256) void k2f(
    const unsigned short* __restrict__ emb_bf,
    const unsigned short* __restrict__ xlT_bf,
    const float* __restrict__ sq,
    const float* __restrict__ tempp, const float* __restrict__ thetap,
    float* __restrict__ adjw,      // [2048][2048] f32
    float* __restrict__ outPart,   // [8][2048][128]
    float* __restrict__ degPart,   // [8][2048]
    int* __restrict__ cnt,         // [128]
    float* __restrict__ out)       // [2048][128] final
{
    constexpr int LDP = 132;
    __shared__ float Pt[2][16 * LDP];
    __shared__ float degS[4][16];
    __shared__ float dinvS[16];
    __shared__ int lastFlag;

    const int t = threadIdx.x;
    const int lane = t & 63;
    const int w = t >> 6;
    const int m = lane & 15;
    const int q = lane >> 4;
    const int bi = blockIdx.x;
    const int i0 = bi * 16;
    const int bj = blockIdx.y;
    const int jstrip0 = bj * 256;
    const float scale = 1.0f + tempp[0];
    const float bias = 5.0f + thetap[0];

    bf16x8 a0 = *(const bf16x8*)(emb_bf + (size_t)(i0 + m) * 64 + q * 8);
    bf16x8 a1 = *(const bf16x8*)(emb_bf + (size_t)(i0 + m) * 64 + 32 + q * 8);
    float sqIr[4];
    #pragma unroll
    for (int r = 0; r < 4; ++r) sqIr[r] = sq[i0 + q * 4 + r];

    f32x4 accO0 = {0.f, 0.f, 0.f, 0.f};
    f32x4 accO1 = {0.f, 0.f, 0.f, 0.f};
    float dega[4] = {0.f, 0.f, 0.f, 0.f};
    const int cg = w * 32;

    #pragma unroll
    for (int jt = 0; jt < 2; ++jt) {
        const int j0 = jstrip0 + jt * 128;
        float* P = &Pt[jt][0];

        #pragma unroll
        for (int s = 0; s < 2; ++s) {
            const int col = (w * 2 + s) * 16 + m;
            const unsigned short* ebj = emb_bf + (size_t)(j0 + col) * 64;
            bf16x8 b0 = *(const bf16x8*)(ebj + q * 8);
            bf16x8 b1 = *(const bf16x8*)(ebj + 32 + q * 8);
            f32x4 S = {0.f, 0.f, 0.f, 0.f};
            S = __builtin_amdgcn_mfma_f32_16x16x32_bf16(a0, b0, S, 0, 0, 0);
            S = __builtin_amdgcn_mfma_f32_16x16x32_bf16(a1, b1, S, 0, 0, 0);

            const float csqJ = sq[j0 + col];
            const int gcol = j0 + col;
            #pragma unroll
            for (int r = 0; r < 4; ++r) {
                int grow = i0 + q * 4 + r;
                float dist = 2.0f * S[r] - sqIr[r] - csqJ;
                float z = scale * dist + bias;
                float p = 1.0f / (1.0f + __expf(-z));
                if (grow == gcol) p += 1.0f;
                dega[r] += p;
                P[(q * 4 + r) * LDP + col] = p;
            }
        }
        __syncthreads();

        // adjw store: coalesced 128B lines, nontemporal
        {
            int row = t >> 4;
            int c0 = (t & 15) * 8;
            f32x4 v0 = *(const f32x4*)(&P[row * LDP + c0]);
            f32x4 v1 = *(const f32x4*)(&P[row * LDP + c0 + 4]);
            f32x4* dst = (f32x4*)(adjw + (size_t)(i0 + row) * 2048 + j0 + c0);
            __builtin_nontemporal_store(v0, dst);
            __builtin_nontemporal_store(v1, dst + 1);
        }

        // AX: acc += P(16x128) @ xlT(cols cg..cg+31, K=128)
        #pragma unroll
        for (int s = 0; s < 4; ++s) {
            float af[8];
            *(f32x4*)(&af[0]) = *(const f32x4*)(&P[m * LDP + s * 32 + q * 8]);
            *(f32x4*)(&af[4]) = *(const f32x4*)(&P[m * LDP + s * 32 + q * 8 + 4]);
            bf16x8 aa = pack_bf8(af);
            const int k = j0 + s * 32 + q * 8;
            bf16x8 b0 = *(const bf16x8*)(xlT_bf + (size_t)(cg + m) * 2048 + k);
            bf16x8 b1 = *(const bf16x8*)(xlT_bf + (size_t)(cg + 16 + m) * 2048 + k);
            accO0 = __builtin_amdgcn_mfma_f32_16x16x32_bf16(aa, b0, accO0, 0, 0, 0);
            accO1 = __builtin_amdgcn_mfma_f32_16x16x32_bf16(aa, b1, accO1, 0, 0, 0);
        }
    }

    // deg partial: reduce over m-lanes, combine 4 waves via LDS, plain store
    #pragma unroll
    for (int r = 0; r < 4; ++r) {
        float v = dega[r];
        v += __shfl_xor(v, 1);
        v += __shfl_xor(v, 2);
        v += __shfl_xor(v, 4);
        v += __shfl_xor(v, 8);
        if (m == 0) degS[w][q * 4 + r] = v;
    }
    __syncthreads();
    if (t < 16)
        degPart[bj * 2048 + i0 + t] =
            degS[0][t] + degS[1][t] + degS[2][t] + degS[3][t];

    // out partial: plain stores (block owns [bj][i0..i0+15][*])
    float* op = outPart + ((size_t)bj * 2048 + i0) * 128;
    #pragma unroll
    for (int r = 0; r < 4; ++r) {
        op[(q * 4 + r) * 128 + cg + m] = accO0[r];
        op[(q * 4 + r) * 128 + cg + 16 + m] = accO1[r];
    }

    // ---- last-block-per-i-tile reduction (replaces k3) ----
    __threadfence();            // make this block's partials device-visible
    __syncthreads();            // all threads' fences done before signaling
    if (t == 0) {
        int old = atomicAdd(&cnt[bi], 1);
        lastFlag = (old == 7);
    }
    __syncthreads();
    if (lastFlag) {
        __threadfence();        // acquire side: don't read stale partials
        if (t < 16) {
            float d = 0.f;
            #pragma unroll
            for (int p = 0; p < 8; ++p) d += degPart[p * 2048 + i0 + t];
            dinvS[t] = 1.0f / d;
        }
        __syncthreads();
        const int base = t * 8;          // tile-local element index
        const int row = base >> 7;
        const int col = base & 127;
        float4 s0 = make_float4(0.f, 0.f, 0.f, 0.f);
        float4 s1 = make_float4(0.f, 0.f, 0.f, 0.f);
        #pragma unroll
        for (int p = 0; p < 8; ++p) {
            const float* src = outPart + ((size_t)p * 2048 + i0 + row) * 128 + col;
            float4 a = *(const float4*)(src);
            float4 b = *(const float4*)(src + 4);
            s0.x += a.x; s0.y += a.y; s0.z += a.z; s0.w += a.w;
            s1.x += b.x; s1.y += b.y; s1.z += b.z; s1.w += b.w;
        }
        float dinv = dinvS[row];
        s0.x = fmaxf(s0.x * dinv, 0.f); s0.y = fmaxf(s0.y * dinv, 0.f);
        s0.z = fmaxf(s0.z * dinv, 0.f); s0.w = fmaxf(s0.w * dinv, 0.f);
        s1.x = fmaxf(s1.x * dinv, 0.f); s1.y = fmaxf(s1.y * dinv, 0.f);
        s1.z = fmaxf(s1.z * dinv, 0.f); s1.w = fmaxf(s1.w * dinv, 0.f);
        float* dst = out + (size_t)(i0 + row) * 128 + col;
        *(float4*)(dst) = s0;
        *(float4*)(dst + 4) = s1;
    }
}

extern "C" void kernel_launch(void* const* d_in, const int* in_sizes, int n_in,
                              void* d_out, int out_size, void* d_ws, size_t ws_size,
                              hipStream_t stream) {
    const float* x     = (const float*)d_in[0];
    const float* W0    = (const float*)d_in[2];
    const float* b0    = (const float*)d_in[3];
    const float* W1    = (const float*)d_in[4];
    const float* b1    = (const float*)d_in[5];
    const float* W2    = (const float*)d_in[6];
    const float* b2    = (const float*)d_in[7];
    const float* temp  = (const float*)d_in[8];
    const float* theta = (const float*)d_in[9];

    char* ws = (char*)d_ws;
    unsigned short* emb_bf = (unsigned short*)(ws);            // 262144 B
    unsigned short* xlT_bf = (unsigned short*)(ws + 262144);   // 524288 B
    float* sq      = (float*)(ws + 786432);                    //   8192 B
    float* degPart = (float*)(ws + 794624);                    //  65536 B
    int*   cnt     = (int*)(ws + 860160);                      //    512 B
    float* outPart = (float*)(ws + 861184);                    // 8 MiB

    float* out  = (float*)d_out;              // [2048*128]
    float* adjw = (float*)d_out + 262144;     // [2048*2048]

    k1_mfma<<<128, 512, 0, stream>>>(x, W0, b0, W1, b1, W2, b2,
                                     emb_bf, xlT_bf, sq, cnt);
    k2f<<<dim3(128, 8), 256, 0, stream>>>(emb_bf, xlT_bf, sq, temp, theta,
                                          adjw, outPart, degPart, cnt, out);
}

// Round 7
// 110.492 us; speedup vs baseline: 2.5138x; 2.5138x over previous
//
#include <hip/hip_runtime.h>
#include <hip/hip_bf16.h>

// N=2048, D_IN=128, H=256, D_EMB=64
// inputs: 0:x 1:adj(unused) 2:W0 3:b0 4:W1 5:b1 6:W2 7:b2 8:temp 9:theta
// d_out: out[2048*128] then adj_wts[2048*2048]

typedef short bf16x8 __attribute__((ext_vector_type(8)));
typedef float f32x4 __attribute__((ext_vector_type(4)));

__device__ __forceinline__ unsigned short f2bf(float f) {
    unsigned u = __float_as_uint(f);
    unsigned r = u + 0x7fffu + ((u >> 16) & 1u);
    return (unsigned short)(r >> 16);
}

// pack 8 f32 -> bf16x8 with round-half-up
__device__ __forceinline__ bf16x8 pack_rne8(const float* p) {
    union { unsigned u[4]; bf16x8 v; } r;
    #pragma unroll
    for (int i = 0; i < 4; ++i) {
        unsigned lo = __float_as_uint(p[2 * i]) + 0x8000u;
        unsigned hi = __float_as_uint(p[2 * i + 1]) + 0x8000u;
        r.u[i] = __builtin_amdgcn_perm(hi, lo, 0x07060302u);
    }
    return r.v;
}

// truncation-pack (for the already-rounded P tile in k2)
__device__ __forceinline__ bf16x8 pack_bf8(const float* p) {
    union { unsigned u[4]; bf16x8 v; } r;
    #pragma unroll
    for (int i = 0; i < 4; ++i)
        r.u[i] = __builtin_amdgcn_perm(__float_as_uint(p[2 * i + 1]),
                                       __float_as_uint(p[2 * i]), 0x07060302u);
    return r.v;
}

// ---------------- Kernel 1: fused MLP via MFMA, 8 waves ----------------
// grid 128 x 512 thr. Block: 16 rows. GEMM0 split over 8 waves; then waves 0-3
// run GEMM1 while waves 4-7 run GEMM2 concurrently. 2 barriers. No fences.
__global__ __launch_bounds__(512) void k1_mfma(
    const float* __restrict__ x,
    const float* __restrict__ W0, const float* __restrict__ b0,
    const float* __restrict__ W1, const float* __restrict__ b1,
    const float* __restrict__ W2, const float* __restrict__ b2,
    unsigned short* __restrict__ emb_bf,   // [2048][64] bf16
    unsigned short* __restrict__ xlT_bf,   // [128][2048] bf16
    float* __restrict__ sq)                // [2048]
{
    constexpr int LDO = 264;               // out_x LDS stride (bf16 elems)
    __shared__ unsigned short oxb[16 * LDO];
    __shared__ float sqs[4][16];

    const int t = threadIdx.x;
    const int lane = t & 63;
    const int w = t >> 6;      // wave 0..7
    const int m = lane & 15;
    const int q = lane >> 4;
    const int i0 = blockIdx.x * 16;

    // A-fragments of x (rows i0+m, K=128), used by GEMM0 (all waves) + GEMM2 (waves 4-7)
    bf16x8 ax[4];
    #pragma unroll
    for (int kb = 0; kb < 4; ++kb) {
        float xf[8];
        *(f32x4*)&xf[0] = *(const f32x4*)(x + (size_t)(i0 + m) * 128 + kb * 32 + q * 8);
        *(f32x4*)&xf[4] = *(const f32x4*)(x + (size_t)(i0 + m) * 128 + kb * 32 + q * 8 + 4);
        ax[kb] = pack_rne8(xf);
    }

    // ---- GEMM0: out_x = relu(x @ W0 + b0), wave w covers cols w*32..w*32+31 ----
    #pragma unroll
    for (int hh = 0; hh < 2; ++hh) {
        const int h = (w * 2 + hh) * 16 + m;
        float bb = b0[h];
        f32x4 acc = {bb, bb, bb, bb};
        #pragma unroll
        for (int kb = 0; kb < 4; ++kb) {
            float wf[8];
            #pragma unroll
            for (int j = 0; j < 8; ++j) wf[j] = W0[(size_t)(kb * 32 + q * 8 + j) * 256 + h];
            acc = __builtin_amdgcn_mfma_f32_16x16x32_bf16(ax[kb], pack_rne8(wf), acc, 0, 0, 0);
        }
        #pragma unroll
        for (int r = 0; r < 4; ++r)
            oxb[(q * 4 + r) * LDO + h] = f2bf(fmaxf(acc[r], 0.0f));
    }
    __syncthreads();

    if (w < 4) {
        // ---- GEMM1 (waves 0-3): emb = relu(out_x @ W1 + b1), cols w*16..w*16+15 ----
        const int h = w * 16 + m;
        float bb = b1[h];
        f32x4 acc = {bb, bb, bb, bb};
        #pragma unroll
        for (int kb = 0; kb < 8; ++kb) {
            bf16x8 af = *(const bf16x8*)(&oxb[m * LDO + kb * 32 + q * 8]);
            float wf[8];
            #pragma unroll
            for (int j = 0; j < 8; ++j) wf[j] = W1[(size_t)(kb * 32 + q * 8 + j) * 64 + h];
            acc = __builtin_amdgcn_mfma_f32_16x16x32_bf16(af, pack_rne8(wf), acc, 0, 0, 0);
        }
        float s2[4];
        #pragma unroll
        for (int r = 0; r < 4; ++r) {
            float e = fmaxf(acc[r], 0.0f);
            emb_bf[(size_t)(i0 + q * 4 + r) * 64 + h] = f2bf(e);
            s2[r] = e * e;
        }
        #pragma unroll
        for (int r = 0; r < 4; ++r) {
            float v = s2[r];
            v += __shfl_xor(v, 1);
            v += __shfl_xor(v, 2);
            v += __shfl_xor(v, 4);
            v += __shfl_xor(v, 8);
            if (m == 0) sqs[w][q * 4 + r] = v;
        }
    } else {
        // ---- GEMM2 (waves 4-7): x_last = x @ W2 + b2, cols (w-4)*32..+31 ----
        const int w2 = w - 4;
        #pragma unroll
        for (int hh = 0; hh < 2; ++hh) {
            const int c = (w2 * 2 + hh) * 16 + m;
            float bb = b2[c];
            f32x4 acc = {bb, bb, bb, bb};
            #pragma unroll
            for (int kb = 0; kb < 4; ++kb) {
                float wf[8];
                #pragma unroll
                for (int j = 0; j < 8; ++j) wf[j] = W2[(size_t)(kb * 32 + q * 8 + j) * 128 + c];
                acc = __builtin_amdgcn_mfma_f32_16x16x32_bf16(ax[kb], pack_rne8(wf), acc, 0, 0, 0);
            }
            uint2 pk;
            pk.x = (unsigned)f2bf(acc[0]) | ((unsigned)f2bf(acc[1]) << 16);
            pk.y = (unsigned)f2bf(acc[2]) | ((unsigned)f2bf(acc[3]) << 16);
            *(uint2*)(&xlT_bf[(size_t)c * 2048 + i0 + q * 4]) = pk;
        }
    }
    __syncthreads();
    if (t < 16)
        sq[i0 + t] = sqs[0][t] + sqs[1][t] + sqs[2][t] + sqs[3][t];
}

// ---------------- Kernel 2: fused adjacency + A@x_last (partial stores) ----------------
// grid (128 i-tiles, 8 j-strips) x 256 thr. Block: 16 rows x 256 cols in 2 iters.
// ONE barrier per iteration; no atomics, no fences.
__global__ __launch_bounds__(256) void k2f(
    const unsigned short* __restrict__ emb_bf,
    const unsigned short* __restrict__ xlT_bf,
    const float* __restrict__ sq,
    const float* __restrict__ tempp, const float* __restrict__ thetap,
    float* __restrict__ adjw,      // [2048][2048] f32
    float* __restrict__ outPart,   // [8][2048][128]
    float* __restrict__ degPart)   // [8][2048]
{
    constexpr int LDP = 132;
    __shared__ float Pt[2][16 * LDP];
    __shared__ float degS[4][16];

    const int t = threadIdx.x;
    const int lane = t & 63;
    const int w = t >> 6;
    const int m = lane & 15;
    const int q = lane >> 4;
    const int i0 = blockIdx.x * 16;
    const int bj = blockIdx.y;
    const int jstrip0 = bj * 256;
    const float scale = 1.0f + tempp[0];
    const float bias = 5.0f + thetap[0];

    bf16x8 a0 = *(const bf16x8*)(emb_bf + (size_t)(i0 + m) * 64 + q * 8);
    bf16x8 a1 = *(const bf16x8*)(emb_bf + (size_t)(i0 + m) * 64 + 32 + q * 8);
    float sqIr[4];
    #pragma unroll
    for (int r = 0; r < 4; ++r) sqIr[r] = sq[i0 + q * 4 + r];

    f32x4 accO0 = {0.f, 0.f, 0.f, 0.f};
    f32x4 accO1 = {0.f, 0.f, 0.f, 0.f};
    float dega[4] = {0.f, 0.f, 0.f, 0.f};
    const int cg = w * 32;

    #pragma unroll
    for (int jt = 0; jt < 2; ++jt) {
        const int j0 = jstrip0 + jt * 128;
        float* P = &Pt[jt][0];

        #pragma unroll
        for (int s = 0; s < 2; ++s) {
            const int col = (w * 2 + s) * 16 + m;
            const unsigned short* ebj = emb_bf + (size_t)(j0 + col) * 64;
            bf16x8 b0 = *(const bf16x8*)(ebj + q * 8);
            bf16x8 b1 = *(const bf16x8*)(ebj + 32 + q * 8);
            f32x4 S = {0.f, 0.f, 0.f, 0.f};
            S = __builtin_amdgcn_mfma_f32_16x16x32_bf16(a0, b0, S, 0, 0, 0);
            S = __builtin_amdgcn_mfma_f32_16x16x32_bf16(a1, b1, S, 0, 0, 0);

            const float csqJ = sq[j0 + col];
            const int gcol = j0 + col;
            #pragma unroll
            for (int r = 0; r < 4; ++r) {
                int grow = i0 + q * 4 + r;
                float dist = 2.0f * S[r] - sqIr[r] - csqJ;
                float z = scale * dist + bias;
                float p = 1.0f / (1.0f + __expf(-z));
                if (grow == gcol) p += 1.0f;
                dega[r] += p;
                P[(q * 4 + r) * LDP + col] = p;
            }
        }
        __syncthreads();

        // adjw store: coalesced 128B lines, nontemporal
        {
            int row = t >> 4;
            int c0 = (t & 15) * 8;
            f32x4 v0 = *(const f32x4*)(&P[row * LDP + c0]);
            f32x4 v1 = *(const f32x4*)(&P[row * LDP + c0 + 4]);
            f32x4* dst = (f32x4*)(adjw + (size_t)(i0 + row) * 2048 + j0 + c0);
            __builtin_nontemporal_store(v0, dst);
            __builtin_nontemporal_store(v1, dst + 1);
        }

        // AX: acc += P(16x128) @ xlT(cols cg..cg+31, K=128)
        #pragma unroll
        for (int s = 0; s < 4; ++s) {
            float af[8];
            *(f32x4*)(&af[0]) = *(const f32x4*)(&P[m * LDP + s * 32 + q * 8]);
            *(f32x4*)(&af[4]) = *(const f32x4*)(&P[m * LDP + s * 32 + q * 8 + 4]);
            bf16x8 aa = pack_bf8(af);
            const int k = j0 + s * 32 + q * 8;
            bf16x8 b0 = *(const bf16x8*)(xlT_bf + (size_t)(cg + m) * 2048 + k);
            bf16x8 b1 = *(const bf16x8*)(xlT_bf + (size_t)(cg + 16 + m) * 2048 + k);
            accO0 = __builtin_amdgcn_mfma_f32_16x16x32_bf16(aa, b0, accO0, 0, 0, 0);
            accO1 = __builtin_amdgcn_mfma_f32_16x16x32_bf16(aa, b1, accO1, 0, 0, 0);
        }
    }

    // deg partial: reduce over m-lanes, combine 4 waves via LDS, plain store
    #pragma unroll
    for (int r = 0; r < 4; ++r) {
        float v = dega[r];
        v += __shfl_xor(v, 1);
        v += __shfl_xor(v, 2);
        v += __shfl_xor(v, 4);
        v += __shfl_xor(v, 8);
        if (m == 0) degS[w][q * 4 + r] = v;
    }
    __syncthreads();
    if (t < 16)
        degPart[bj * 2048 + i0 + t] =
            degS[0][t] + degS[1][t] + degS[2][t] + degS[3][t];

    // out partial: plain stores (block owns [bj][i0..i0+15][*])
    float* op = outPart + ((size_t)bj * 2048 + i0) * 128;
    #pragma unroll
    for (int r = 0; r < 4; ++r) {
        op[(q * 4 + r) * 128 + cg + m] = accO0[r];
        op[(q * 4 + r) * 128 + cg + 16 + m] = accO1[r];
    }
}

// ---------------- Kernel 3: out = relu(sum_p outPart / sum_p degPart) ----------------
__global__ __launch_bounds__(256) void k3_fin(
    const float* __restrict__ outPart, const float* __restrict__ degPart,
    float* __restrict__ out)
{
    int idx4 = (blockIdx.x * 256 + threadIdx.x) * 4;
    int row = idx4 >> 7;
    float4 s = make_float4(0.f, 0.f, 0.f, 0.f);
    float d = 0.f;
    #pragma unroll
    for (int p = 0; p < 8; ++p) {
        float4 v = *(const float4*)(&outPart[(size_t)p * 262144 + idx4]);
        s.x += v.x; s.y += v.y; s.z += v.z; s.w += v.w;
        d += degPart[p * 2048 + row];
    }
    float dinv = 1.0f / d;
    s.x = fmaxf(s.x * dinv, 0.f);
    s.y = fmaxf(s.y * dinv, 0.f);
    s.z = fmaxf(s.z * dinv, 0.f);
    s.w = fmaxf(s.w * dinv, 0.f);
    *(float4*)(&out[idx4]) = s;
}

extern "C" void kernel_launch(void* const* d_in, const int* in_sizes, int n_in,
                              void* d_out, int out_size, void* d_ws, size_t ws_size,
                              hipStream_t stream) {
    const float* x     = (const float*)d_in[0];
    const float* W0    = (const float*)d_in[2];
    const float* b0    = (const float*)d_in[3];
    const float* W1    = (const float*)d_in[4];
    const float* b1    = (const float*)d_in[5];
    const float* W2    = (const float*)d_in[6];
    const float* b2    = (const float*)d_in[7];
    const float* temp  = (const float*)d_in[8];
    const float* theta = (const float*)d_in[9];

    char* ws = (char*)d_ws;
    unsigned short* emb_bf = (unsigned short*)(ws);            // 262144 B
    unsigned short* xlT_bf = (unsigned short*)(ws + 262144);   // 524288 B
    float* sq      = (float*)(ws + 786432);                    //   8192 B
    float* degPart = (float*)(ws + 794624);                    //  65536 B
    float* outPart = (float*)(ws + 860160);                    // 8 MiB

    float* out  = (float*)d_out;              // [2048*128]
    float* adjw = (float*)d_out + 262144;     // [2048*2048]

    k1_mfma<<<128, 512, 0, stream>>>(x, W0, b0, W1, b1, W2, b2,
                                     emb_bf, xlT_bf, sq);
    k2f<<<dim3(128, 8), 256, 0, stream>>>(emb_bf, xlT_bf, sq, temp, theta,
                                          adjw, outPart, degPart);
    k3_fin<<<256, 256, 0, stream>>>(outPart, degPart, out);
}